// Round 5
// baseline (888.220 us; speedup 1.0000x reference)
//
#include <hip/hip_runtime.h>

// MaskedBatchNorm2d: B=16, C=64, W=256, H=256, fp32.
// Identity: masked-out locations are exactly +/-0 in all channels, so masked
// per-channel sums == full sums and out = x*inv[c] everywhere (exact-
// cancellation "dirty" locations handled by a ~never-taken fixup path).
//
// R1: global atomics removed (823us -> 594us).
// R2 FAILED: (256,8) launch bounds spilled 32-reg accumulators (+500MB scratch).
// R3: 512thr/8ch-per-wave pass1, no spill (594 -> 564; pass1 ~157us). VERIFIED.
// R4 FAILED: per-load LDS atomics serialized the stream (pass1 382us).
// R5 FAILED: cooperative launch at exact capacity silently failed -> out=0.
// R6 (this round): R3 structure, no coop. pass1 stages ALL 4 tiles in LDS
// before one combine phase (8 barriers -> 5); dirty detect via predicated
// atomicOr of abs-bits (~70% of locations all-zero -> no atomic issued);
// finalize fused into pass1's LAST block via threadfence-ticket (CUB/rocPRIM
// pattern, device-scope atomics). pass2 byte-identical to verified R3.

#define NB 16
#define CB 64
#define WH 65536               // W*H
#define TILE 256               // locations per tile
#define NTILES (NB * WH / TILE)  // 4096
#define GRID1 1024
#define TPT (NTILES / GRID1)   // 4 tiles per block
#define DIRTY_CAP 512
#define EPS 0.001f

typedef float f32x4 __attribute__((ext_vector_type(4)));

// ws layout (float units):
//  [0 .. 131071]        sqPart[1024][128] (S row 0..63, Q row 64..127) - 512 KB
//  [131072 .. 147455]   nPart[1024][16]   (uint)                      -  64 KB
//  [147456]             dirtyCnt (uint)   } one 64-byte memset covers both
//  [147457]             ticket   (uint)   }
//  [147520 .. 147583]   inv[64]
//  [147584 .. 147599]   padArr[16] (int)
//  [147600 .. 148111]   dirtyLoc[DIRTY_CAP] (int)

__global__ __launch_bounds__(512, 8)
void mbn_pass1(const float* __restrict__ x, float* __restrict__ sqPart,
               unsigned* __restrict__ nPart, unsigned* __restrict__ dirtyCnt,
               int* __restrict__ dirtyLoc, float* __restrict__ inv,
               int* __restrict__ padArr, unsigned* __restrict__ ticket) {
    __shared__ float    lds_s[TPT][8][TILE];   // 32 KB: per-tile per-wave sums
    __shared__ unsigned lds_or[TPT][TILE];     //  4 KB: per-location abs-bit OR
    __shared__ unsigned cnt_lds[16];
    __shared__ unsigned lastFlag;
    const int tid  = threadIdx.x;        // 0..511
    const int wave = tid >> 6;           // 0..7
    const int lane = tid & 63;

    for (int i = tid; i < TPT * TILE; i += 512) ((unsigned*)lds_or)[i] = 0u;
    if (tid < 16) cnt_lds[tid] = 0;
    if (tid == 0) lastFlag = 0;

    float sAcc[8], qAcc[8];              // per-channel S/Q (this wave's 8 ch)
#pragma unroll
    for (int j = 0; j < 8; ++j) { sAcc[j] = 0.f; qAcc[j] = 0.f; }
    __syncthreads();                                              // barrier 1

    // ---- load/accumulate: ALL 4 tiles, zero barriers inside ----
#pragma unroll
    for (int tt = 0; tt < TPT; ++tt) {
        const int tile = blockIdx.x + tt * GRID1;
        const int b    = tile >> 8;                 // 256 tiles per batch
        const int whb  = (tile & 255) * TILE;
        const float* base = x + (((size_t)(b * 64 + wave * 8)) << 16) + whb + lane * 4;

        float sp0 = 0.f, sp1 = 0.f, sp2 = 0.f, sp3 = 0.f;
        unsigned o0 = 0u, o1 = 0u, o2 = 0u, o3 = 0u;
#pragma unroll
        for (int j = 0; j < 8; ++j) {
            float4 v = *(const float4*)(base + ((size_t)j << 16));
            sp0 += v.x; sp1 += v.y; sp2 += v.z; sp3 += v.w;
            o0 |= __float_as_uint(v.x) & 0x7fffffffu;
            o1 |= __float_as_uint(v.y) & 0x7fffffffu;
            o2 |= __float_as_uint(v.z) & 0x7fffffffu;
            o3 |= __float_as_uint(v.w) & 0x7fffffffu;
            sAcc[j] += (v.x + v.y) + (v.z + v.w);
            qAcc[j] = fmaf(v.x, v.x, qAcc[j]);
            qAcc[j] = fmaf(v.y, v.y, qAcc[j]);
            qAcc[j] = fmaf(v.z, v.z, qAcc[j]);
            qAcc[j] = fmaf(v.w, v.w, qAcc[j]);
        }
        *(float4*)&lds_s[tt][wave][lane * 4] = make_float4(sp0, sp1, sp2, sp3);
        // ~70% of locations are fully zero across channels -> no atomic issued
        if (o0) atomicOr(&lds_or[tt][lane * 4 + 0], o0);
        if (o1) atomicOr(&lds_or[tt][lane * 4 + 1], o1);
        if (o2) atomicOr(&lds_or[tt][lane * 4 + 2], o2);
        if (o3) atomicOr(&lds_or[tt][lane * 4 + 3], o3);
    }
    __syncthreads();                                              // barrier 2

    // ---- combine: 1024 (tile,loc) pairs, 2 per thread; wave-uniform tile ----
#pragma unroll
    for (int h = 0; h < 2; ++h) {
        const int pi  = tid + h * 512;             // 0..1023
        const int tt  = pi >> 8, loc = pi & 255;
        const int tile = blockIdx.x + tt * GRID1;
        const int b    = tile >> 8;
        float s = ((lds_s[tt][0][loc] + lds_s[tt][1][loc])
                 + (lds_s[tt][2][loc] + lds_s[tt][3][loc]))
                + ((lds_s[tt][4][loc] + lds_s[tt][5][loc])
                 + (lds_s[tt][6][loc] + lds_s[tt][7][loc]));
        bool kept = (s != 0.0f);
        unsigned long long bal = __ballot(kept);
        if (lane == 0) atomicAdd(&cnt_lds[b], (unsigned)__popcll(bal));
        if (!kept && lds_or[tt][loc] != 0u) {      // exact cancellation: ~never
            unsigned di = atomicAdd(dirtyCnt, 1u);
            if (di < DIRTY_CAP) dirtyLoc[di] = (b << 16) | ((tile & 255) * TILE + loc);
        }
    }

    // wave-reduce register accumulators; plain stores to this block's ws row
#pragma unroll
    for (int j = 0; j < 8; ++j) {
        float sv = sAcc[j], qv = qAcc[j];
        for (int off = 32; off; off >>= 1) {
            sv += __shfl_xor(sv, off);
            qv += __shfl_xor(qv, off);
        }
        if (lane == 0) {
            sqPart[blockIdx.x * 128 + wave * 8 + j]      = sv;   // S at col c
            sqPart[blockIdx.x * 128 + 64 + wave * 8 + j] = qv;   // Q at 64+c
        }
    }
    __syncthreads();                                              // barrier 3
    if (tid < 16) nPart[blockIdx.x * 16 + tid] = cnt_lds[tid];

    // ---- last-block-done finalize (threadfence-ticket pattern) ----
    __threadfence();                     // each thread's global stores -> device
    __syncthreads();                                              // barrier 4
    if (tid == 0) {
        unsigned t = atomicAdd(ticket, 1u);
        if (t == GRID1 - 1) lastFlag = 1u;
    }
    __syncthreads();                                              // barrier 5
    if (!lastFlag) return;

    // ======== finalize: runs in exactly ONE block, 512 threads ========
    __threadfence();                     // acquire side
    float*    red  = (float*)&lds_s[0][0][0];        // 512 floats (reuse LDS)
    float*    sq   = red + 512;                      // 128 floats
    unsigned* npar = (unsigned*)(sq + 128);          // 16*16 uints
    unsigned* ntot = npar + 256;                     // 16 uints

    const int col = tid & 127, grp = tid >> 7;       // 4 groups x 256 rows
    {
        float acc = 0.f;
        const float* p = sqPart + (size_t)grp * 256 * 128 + col;
#pragma unroll 8
        for (int r = 0; r < 256; ++r) acc += p[(size_t)r * 128];
        red[tid] = acc;
    }
    if (tid < 256) {                     // mask counts: 16 groups x 16 batches
        const int b = tid & 15, g2 = tid >> 4;
        unsigned s = 0;
        const unsigned* np = nPart + g2 * 64 * 16 + b;
#pragma unroll 8
        for (int r = 0; r < 64; ++r) s += np[r * 16];
        npar[g2 * 16 + b] = s;
    }
    __syncthreads();
    if (tid < 128) sq[tid] = (red[tid] + red[128 + tid]) + (red[256 + tid] + red[384 + tid]);
    if (tid < 16) {
        unsigned v = 0;
#pragma unroll
        for (int g2 = 0; g2 < 16; ++g2) v += npar[g2 * 16 + tid];
        ntot[tid] = v;
    }
    __syncthreads();

    if (tid < 64) {
        const int c = tid;
        unsigned nmax = 0;
#pragma unroll
        for (int b = 0; b < NB; ++b) { unsigned nb = ntot[b]; nmax = nb > nmax ? nb : nmax; }
        const float total = (float)(16u * nmax);   // B*Nmax, exact in fp32

        float s = sq[c], q = sq[64 + c];
        // dirty corrections (exclude exact-cancellation locs) — ~never runs
        unsigned cnt = *dirtyCnt; if (cnt > DIRTY_CAP) cnt = DIRTY_CAP;
        for (unsigned i = 0; i < cnt; ++i) {
            int loc = dirtyLoc[i];
            int b = loc >> 16, wh = loc & 65535;
            float v = x[(((size_t)(b * 64 + c)) << 16) + wh];
            s -= v; q -= v * v;
        }
        float p1 = 0.f, p2 = 0.f;
#pragma unroll
        for (int b = 0; b < NB; ++b) {
            float padf = (float)(nmax - ntot[b]);
            float v00  = x[((size_t)(b * 64 + c)) << 16];
            p1 = fmaf(padf, v00, p1);
            p2 = fmaf(padf, v00 * v00, p2);
            if (c == 0) padArr[b] = (int)(nmax - ntot[b]);
        }
        float mean = (s + p1) / total;
        float var  = (q + p2) / total - mean * mean;   // algebraic identity
        inv[c] = 1.0f / sqrtf(var + EPS);
    }
}

__global__ __launch_bounds__(256)
void mbn_pass2(const float* __restrict__ x, float* __restrict__ out,
               const float* __restrict__ inv, const unsigned* __restrict__ dirtyCnt,
               const int* __restrict__ dirtyLoc, const int* __restrict__ padArr) {
    // 8192 blocks x 2048 float4: each block's chunk lies in ONE channel plane
    const int blk = blockIdx.x;
    const float sc = inv[(blk >> 3) & 63];             // 8 blocks per plane
    const f32x4* x4 = (const f32x4*)x;
    f32x4* out4 = (f32x4*)out;
    const size_t base = (size_t)blk * 2048 + threadIdx.x;
#pragma unroll
    for (int k = 0; k < 8; ++k) {
        size_t i = base + (size_t)k * 256;
        f32x4 v = x4[i];
        v *= sc;
        __builtin_nontemporal_store(v, &out4[i]);      // out never re-read
    }

    // folded fixup: each block patches only its OWN float range. dirtyCnt == 0
    // in practice -> uniform early out.
    unsigned cnt = *dirtyCnt;
    if (cnt != 0) {
        __syncthreads();                               // order NT stores vs patch
        if (threadIdx.x == 0) {
            if (cnt > DIRTY_CAP) cnt = DIRTY_CAP;
            const int bb = blk >> 9, cc = (blk >> 3) & 63, seg = blk & 7;
            const int lo = seg * 8192, hi = lo + 8192;
            for (unsigned i = 0; i < cnt; ++i) {
                int loc = dirtyLoc[i];
                int b = loc >> 16, wh = loc & 65535;
                if (b != bb || wh < lo || wh >= hi) continue;
                if (wh == 0 && padArr[b] > 0) continue;   // (0,0) override wins
                size_t idx = (((size_t)(b * 64 + cc)) << 16) + wh;
                out[idx] = x[idx];                        // m=0 w/ nonzero x: out = x
            }
        }
    }
}

extern "C" void kernel_launch(void* const* d_in, const int* in_sizes, int n_in,
                              void* d_out, int out_size, void* d_ws, size_t ws_size,
                              hipStream_t stream) {
    const float* x = (const float*)d_in[0];
    float* out = (float*)d_out;
    float* wsf = (float*)d_ws;

    float*    sqPart   = wsf;
    unsigned* nPart    = (unsigned*)(wsf + 131072);
    unsigned* dirtyCnt = (unsigned*)(wsf + 147456);
    unsigned* ticket   = dirtyCnt + 1;
    float*    inv      = wsf + 147520;
    int*      padArr   = (int*)(wsf + 147584);
    int*      dirtyLoc = (int*)(wsf + 147600);

    // zero dirtyCnt + ticket (same 64-byte line)
    hipMemsetAsync((char*)d_ws + 147456 * 4, 0, 64, stream);

    mbn_pass1<<<GRID1, 512, 0, stream>>>(x, sqPart, nPart, dirtyCnt, dirtyLoc,
                                         inv, padArr, ticket);
    mbn_pass2<<<8192, 256, 0, stream>>>(x, out, inv, dirtyCnt, dirtyLoc, padArr);
}

// Round 7
// 792.757 us; speedup vs baseline: 1.1204x; 1.1204x over previous
//
#include <hip/hip_runtime.h>

// MaskedBatchNorm2d: B=16, C=64, W=256, H=256, fp32.
// Identity: masked-out locations are exactly +/-0 in all channels, so masked
// per-channel sums == full sums and out = x*inv[c] everywhere (exact-
// cancellation "dirty" locations handled by a ~never-taken fixup path).
//
// R1: global atomics removed (823us -> 594us).
// R2 FAILED: (256,8) min-waves=8 -> 64-reg budget -> spill (+500MB scratch).
// R3: 512thr/8ch-per-wave pass1 (594 -> 564; pass1 ~157us) - but also (512,8),
//     so likely MILDLY spilled; un-spilled R3 body never measured.
// R4 FAILED: per-load LDS atomics serialized the stream (pass1 382us).
// R5 FAILED: cooperative launch at exact capacity silently failed -> out=0.
// R6 FAILED: staged body @ (512,8) -> heavy spill (VGPR 32, FETCH +143MB,
//     pass1 510us). BUT: ticket-based finalize fusion verified correct on HW.
// R7: ONE lever - R3's proven body at __launch_bounds__(512,4) (128-reg
//     budget, cannot spill; 2 blocks/CU). Bench was an infra failure
//     ("container failed twice") - no data. R8 resubmits IDENTICAL source.

#define NB 16
#define CB 64
#define WH 65536               // W*H
#define TILE 256               // locations per tile
#define NTILES (NB * WH / TILE)  // 4096
#define GRID1 1024
#define TPT (NTILES / GRID1)   // 4 tiles per block
#define DIRTY_CAP 512
#define EPS 0.001f

typedef float f32x4 __attribute__((ext_vector_type(4)));

// ws layout (float units):
//  [0 .. 131071]        sqPart[1024][128] (S row 0..63, Q row 64..127) - 512 KB
//  [131072 .. 147455]   nPart[1024][16]   (uint)                      -  64 KB
//  [147456]             dirtyCnt (uint)   } one 64-byte memset covers both
//  [147457]             ticket   (uint)   }
//  [147520 .. 147583]   inv[64]
//  [147584 .. 147599]   padArr[16] (int)
//  [147600 .. 148111]   dirtyLoc[DIRTY_CAP] (int)

__global__ __launch_bounds__(512, 4)
void mbn_pass1(const float* __restrict__ x, float* __restrict__ sqPart,
               unsigned* __restrict__ nPart, unsigned* __restrict__ dirtyCnt,
               int* __restrict__ dirtyLoc, float* __restrict__ inv,
               int* __restrict__ padArr, unsigned* __restrict__ ticket) {
    // 8 waves x 8 channels each. LDS: 8 partial rows x 256 loc x {s,a} = 16KB.
    __shared__ float lds_s[8][TILE];
    __shared__ float lds_a[8][TILE];
    __shared__ unsigned cnt_lds[16];
    __shared__ unsigned lastFlag;
    const int tid  = threadIdx.x;       // 0..511
    const int wave = tid >> 6;          // 0..7
    const int lane = tid & 63;
    if (tid < 16) cnt_lds[tid] = 0;
    if (tid == 0) lastFlag = 0;

    float sAcc[8], qAcc[8];             // per-channel S/Q for this wave's 8 ch
#pragma unroll
    for (int j = 0; j < 8; ++j) { sAcc[j] = 0.f; qAcc[j] = 0.f; }
    __syncthreads();

    for (int tt = 0; tt < TPT; ++tt) {
        const int tile = blockIdx.x + tt * GRID1;
        const int b    = tile >> 8;                 // 256 tiles per batch
        const int whb  = (tile & 255) * TILE;
        const float* base = x + (((size_t)(b * 64 + wave * 8)) << 16) + whb + lane * 4;

        float sp0 = 0.f, sp1 = 0.f, sp2 = 0.f, sp3 = 0.f;
        float aa0 = 0.f, aa1 = 0.f, aa2 = 0.f, aa3 = 0.f;
#pragma unroll
        for (int j = 0; j < 8; ++j) {
            float4 v = *(const float4*)(base + ((size_t)j << 16));
            sp0 += v.x; sp1 += v.y; sp2 += v.z; sp3 += v.w;
            aa0 += fabsf(v.x); aa1 += fabsf(v.y); aa2 += fabsf(v.z); aa3 += fabsf(v.w);
            sAcc[j] += (v.x + v.y) + (v.z + v.w);
            qAcc[j] = fmaf(v.x, v.x, qAcc[j]);
            qAcc[j] = fmaf(v.y, v.y, qAcc[j]);
            qAcc[j] = fmaf(v.z, v.z, qAcc[j]);
            qAcc[j] = fmaf(v.w, v.w, qAcc[j]);
        }
        *(float4*)&lds_s[wave][lane * 4] = make_float4(sp0, sp1, sp2, sp3);
        *(float4*)&lds_a[wave][lane * 4] = make_float4(aa0, aa1, aa2, aa3);
        __syncthreads();

        // combine: thread t (t<256) owns location t of the tile
        if (tid < TILE) {
            float s = (lds_s[0][tid] + lds_s[1][tid]) + (lds_s[2][tid] + lds_s[3][tid])
                    + (lds_s[4][tid] + lds_s[5][tid]) + (lds_s[6][tid] + lds_s[7][tid]);
            float a = (lds_a[0][tid] + lds_a[1][tid]) + (lds_a[2][tid] + lds_a[3][tid])
                    + (lds_a[4][tid] + lds_a[5][tid]) + (lds_a[6][tid] + lds_a[7][tid]);
            bool mask = (s != 0.0f);
            unsigned long long bal = __ballot(mask);
            if (lane == 0) atomicAdd(&cnt_lds[b], (unsigned)__popcll(bal));  // LDS atomic
            if (!mask && a != 0.0f) {                   // exact cancellation: ~never
                unsigned idx = atomicAdd(dirtyCnt, 1u);
                if (idx < DIRTY_CAP) dirtyLoc[idx] = (b << 16) | (whb + tid);
            }
        }
        __syncthreads();
    }

    // wave-reduce register accumulators; plain stores to this block's ws row
#pragma unroll
    for (int j = 0; j < 8; ++j) {
        float sv = sAcc[j], qv = qAcc[j];
        for (int off = 32; off; off >>= 1) {
            sv += __shfl_xor(sv, off);
            qv += __shfl_xor(qv, off);
        }
        if (lane == 0) {
            sqPart[blockIdx.x * 128 + wave * 8 + j]      = sv;   // S at col c
            sqPart[blockIdx.x * 128 + 64 + wave * 8 + j] = qv;   // Q at 64+c
        }
    }
    if (tid < 16) nPart[blockIdx.x * 16 + tid] = cnt_lds[tid];

    // ---- last-block-done finalize (threadfence-ticket, verified in R6) ----
    __threadfence();                     // release: partials -> device scope
    __syncthreads();
    if (tid == 0) {
        unsigned t = atomicAdd(ticket, 1u);
        if (t == GRID1 - 1) lastFlag = 1u;
    }
    __syncthreads();
    if (!lastFlag) return;

    // ======== finalize: runs in exactly ONE block, 512 threads ========
    __threadfence();                     // acquire side
    float*    red  = (float*)&lds_s[0][0];           // 512 floats (reuse LDS)
    float*    sq   = red + 512;                      // 128 floats
    unsigned* npar = (unsigned*)(sq + 128);          // 16*16 uints
    unsigned* ntot = npar + 256;                     // 16 uints

    const int col = tid & 127, grp = tid >> 7;       // 4 groups x 256 rows
    {
        float acc = 0.f;
        const float* p = sqPart + (size_t)grp * 256 * 128 + col;
#pragma unroll 8
        for (int r = 0; r < 256; ++r) acc += p[(size_t)r * 128];
        red[tid] = acc;
    }
    if (tid < 256) {                     // mask counts: 16 groups x 16 batches
        const int b = tid & 15, g2 = tid >> 4;
        unsigned s = 0;
        const unsigned* np = nPart + g2 * 64 * 16 + b;
#pragma unroll 8
        for (int r = 0; r < 64; ++r) s += np[r * 16];
        npar[g2 * 16 + b] = s;
    }
    __syncthreads();
    if (tid < 128) sq[tid] = (red[tid] + red[128 + tid]) + (red[256 + tid] + red[384 + tid]);
    if (tid < 16) {
        unsigned v = 0;
#pragma unroll
        for (int g2 = 0; g2 < 16; ++g2) v += npar[g2 * 16 + tid];
        ntot[tid] = v;
    }
    __syncthreads();

    if (tid < 64) {
        const int c = tid;
        unsigned nmax = 0;
#pragma unroll
        for (int b = 0; b < NB; ++b) { unsigned nb = ntot[b]; nmax = nb > nmax ? nb : nmax; }
        const float total = (float)(16u * nmax);   // B*Nmax, exact in fp32

        float s = sq[c], q = sq[64 + c];
        // dirty corrections (exclude exact-cancellation locs) — ~never runs
        unsigned cnt = *dirtyCnt; if (cnt > DIRTY_CAP) cnt = DIRTY_CAP;
        for (unsigned i = 0; i < cnt; ++i) {
            int loc = dirtyLoc[i];
            int b = loc >> 16, wh = loc & 65535;
            float v = x[(((size_t)(b * 64 + c)) << 16) + wh];
            s -= v; q -= v * v;
        }
        float p1 = 0.f, p2 = 0.f;
#pragma unroll
        for (int b = 0; b < NB; ++b) {
            float padf = (float)(nmax - ntot[b]);
            float v00  = x[((size_t)(b * 64 + c)) << 16];
            p1 = fmaf(padf, v00, p1);
            p2 = fmaf(padf, v00 * v00, p2);
            if (c == 0) padArr[b] = (int)(nmax - ntot[b]);
        }
        float mean = (s + p1) / total;
        float var  = (q + p2) / total - mean * mean;   // algebraic identity
        inv[c] = 1.0f / sqrtf(var + EPS);
    }
}

__global__ __launch_bounds__(256)
void mbn_pass2(const float* __restrict__ x, float* __restrict__ out,
               const float* __restrict__ inv, const unsigned* __restrict__ dirtyCnt,
               const int* __restrict__ dirtyLoc, const int* __restrict__ padArr) {
    // 8192 blocks x 2048 float4: each block's chunk lies in ONE channel plane
    const int blk = blockIdx.x;
    const float sc = inv[(blk >> 3) & 63];             // 8 blocks per plane
    const f32x4* x4 = (const f32x4*)x;
    f32x4* out4 = (f32x4*)out;
    const size_t base = (size_t)blk * 2048 + threadIdx.x;
#pragma unroll
    for (int k = 0; k < 8; ++k) {
        size_t i = base + (size_t)k * 256;
        f32x4 v = x4[i];
        v *= sc;
        __builtin_nontemporal_store(v, &out4[i]);      // out never re-read
    }

    // folded fixup: each block patches only its OWN float range. dirtyCnt == 0
    // in practice -> uniform early out.
    unsigned cnt = *dirtyCnt;
    if (cnt != 0) {
        __syncthreads();                               // order NT stores vs patch
        if (threadIdx.x == 0) {
            if (cnt > DIRTY_CAP) cnt = DIRTY_CAP;
            const int bb = blk >> 9, cc = (blk >> 3) & 63, seg = blk & 7;
            const int lo = seg * 8192, hi = lo + 8192;
            for (unsigned i = 0; i < cnt; ++i) {
                int loc = dirtyLoc[i];
                int b = loc >> 16, wh = loc & 65535;
                if (b != bb || wh < lo || wh >= hi) continue;
                if (wh == 0 && padArr[b] > 0) continue;   // (0,0) override wins
                size_t idx = (((size_t)(b * 64 + cc)) << 16) + wh;
                out[idx] = x[idx];                        // m=0 w/ nonzero x: out = x
            }
        }
    }
}

extern "C" void kernel_launch(void* const* d_in, const int* in_sizes, int n_in,
                              void* d_out, int out_size, void* d_ws, size_t ws_size,
                              hipStream_t stream) {
    const float* x = (const float*)d_in[0];
    float* out = (float*)d_out;
    float* wsf = (float*)d_ws;

    float*    sqPart   = wsf;
    unsigned* nPart    = (unsigned*)(wsf + 131072);
    unsigned* dirtyCnt = (unsigned*)(wsf + 147456);
    unsigned* ticket   = dirtyCnt + 1;
    float*    inv      = wsf + 147520;
    int*      padArr   = (int*)(wsf + 147584);
    int*      dirtyLoc = (int*)(wsf + 147600);

    // zero dirtyCnt + ticket (same 64-byte line)
    hipMemsetAsync((char*)d_ws + 147456 * 4, 0, 64, stream);

    mbn_pass1<<<GRID1, 512, 0, stream>>>(x, sqPart, nPart, dirtyCnt, dirtyLoc,
                                         inv, padArr, ticket);
    mbn_pass2<<<8192, 256, 0, stream>>>(x, out, inv, dirtyCnt, dirtyLoc, padArr);
}